// Round 19
// baseline (34.603 us; speedup 1.0000x reference)
//
#include <hip/hip_runtime.h>
#include <hip/hip_fp16.h>
#include <math.h>

#define V   50000
#define DIM 128
#define BB  512
#define LQ  30
#define RD  200
#define KN  21

typedef __attribute__((ext_vector_type(8))) _Float16 f16x8;  // 8 f16 = 4 VGPRs
typedef __attribute__((ext_vector_type(4))) float f32x4;
typedef __attribute__((ext_vector_type(2))) float f32x2;     // -> v_pk_*_f32

#if __has_builtin(__builtin_amdgcn_exp2f)
#define EXP2F(x) __builtin_amdgcn_exp2f(x)
#else
#define EXP2F(x) __expf((x) * 0.69314718f)
#endif

#define ALPHA 72.1347520f       // 50 * log2(e)
#define E10   22026.4657948f    // 2^(0.2*ALPHA) = e^10

static __device__ __forceinline__ f16x8 as_hfrag(int4 v) {
    return __builtin_bit_cast(f16x8, v);
}
static __device__ __forceinline__ unsigned pk2h(float a, float b) {
    return __builtin_bit_cast(unsigned, __builtin_amdgcn_cvt_pkrtz(a, b));
}
static __device__ __forceinline__ unsigned hscale(unsigned u, __half2 s) {
    return __builtin_bit_cast(unsigned, __hmul2(__builtin_bit_cast(__half2, u), s));
}

// Fused gather+normalize+f16-convert of one embedding row (doc side) — R14 form.
// Lanes (r, g=0..3) jointly hold the row; lane slice = elements ks*32+g*8..+7.
// ss reduced across g via shfl_xor 16/32. RTZ-pack first, then f16 scale.
static __device__ __forceinline__ void gather_row_f16(const float* __restrict__ rowp,
                                                      int g, int4* f) {
    float ss = 0.0f;
#pragma unroll
    for (int ks = 0; ks < 4; ++ks) {
        const float4* p = reinterpret_cast<const float4*>(rowp + ks * 32 + g * 8);
        float4 a = p[0], b = p[1];
        ss = fmaf(a.x, a.x, fmaf(a.y, a.y, fmaf(a.z, a.z, fmaf(a.w, a.w, ss))));
        ss = fmaf(b.x, b.x, fmaf(b.y, b.y, fmaf(b.z, b.z, fmaf(b.w, b.w, ss))));
        f[ks].x = (int)pk2h(a.x, a.y);
        f[ks].y = (int)pk2h(a.z, a.w);
        f[ks].z = (int)pk2h(b.x, b.y);
        f[ks].w = (int)pk2h(b.z, b.w);
    }
    ss += __shfl_xor(ss, 16);
    ss += __shfl_xor(ss, 32);
    const float inv = rsqrtf(fmaxf(ss, 1e-24f));
    const __half2 h2 = __float2half2_rn(inv);
#pragma unroll
    for (int ks = 0; ks < 4; ++ks) {
        f[ks].x = (int)hscale((unsigned)f[ks].x, h2);
        f[ks].y = (int)hscale((unsigned)f[ks].y, h2);
        f[ks].z = (int)hscale((unsigned)f[ks].z, h2);
        f[ks].w = (int)hscale((unsigned)f[ks].w, h2);
    }
}

// Two-leg geometric Gaussian bank (verified R6..R18), packed f32x2
// (x = leg A, kernels 0..9 center mu=-0.5; y = leg B, 10..19 center +0.5),
// 4 independent t*u chains, tree summation. B_j folded in at combine.
// Exact kernel (mu=1, sigma=1e-3) = integer token equality count.
static __device__ __forceinline__ void bank4_pk(f32x4 pv, int4 dt, int qt,
                                                f32x2* ks2, float& cnt) {
    const float mv[4] = {pv[0], pv[1], pv[2], pv[3]};
    const int   dv[4] = {dt.x, dt.y, dt.z, dt.w};
    f32x2 t[4], u[4];
#pragma unroll
    for (int i = 0; i < 4; ++i) {
        float m  = mv[i];
        float dA = m + 0.5f, dB = m - 0.5f;
        float tA = EXP2F(-ALPHA * dA * (dA + 0.9f));   // leg A start (k=0)
        float tB = EXP2F(-ALPHA * dB * (dB + 0.9f));   // leg B start (k=10)
        float uB = EXP2F(14.4269504f * dB);            // 2^(0.2*ALPHA*dB)
        float uA = uB * E10;
        t[i] = f32x2{tA, tB};
        u[i] = f32x2{uA, uB};
        cnt += (dv[i] == qt) ? 1.0f : 0.0f;
    }
#pragma unroll
    for (int k = 0; k < 10; ++k) {
        ks2[k] += (t[0] + t[1]) + (t[2] + t[3]);       // tree: short dep chains
        t[0] *= u[0]; t[1] *= u[1]; t[2] *= u[2]; t[3] *= u[3];
    }
}

// ------------- kernel: R14 core with both pairs merged into one block -------------
// 512 blocks (b) x 512 thr (8 waves). Waves 0-3 = pair 0, waves 4-7 = pair 1
// (per-wave code identical to R14; pair index = wave>>2). Wave wl owns doc cols
// wl*64..+63 of its pair (4 strips of 16; wl==3: 1 strip). mfma(A=D_frag,
// B=Q_frag): C row = dcol (g*4+j), C col = qrow (r); bank reads accumulators
// directly. Q rows for both pairs staged cooperatively into XOR-swizzled LDS.
// In-block combine produces BOTH logits -> sigmoid written straight to out.
__global__ __launch_bounds__(512, 4) void knrm_main(
    const float* __restrict__ emb, const float* __restrict__ W,
    const int* __restrict__ q1, const int* __restrict__ d1,
    const int* __restrict__ q2, const int* __restrict__ d2,
    float* __restrict__ out)
{
    __shared__ int sQtok[2][32];
    __shared__ __align__(16) int sDtok[2][256];
    __shared__ int4 sQ[2][32][16];                 // 2 x 32 rows x 256B f16, swizzled
    __shared__ float kred[2][4][32][KN];           // 21504 B
    __shared__ float lgbuf[2];

    const int b = blockIdx.x;
    const int tid = threadIdx.x;
    const int lane = tid & 63, w = tid >> 6;
    const int p = w >> 2, wl = w & 3;              // pair, wave-within-pair
    const int r = lane & 15, g = lane >> 4;

    const int* qind = (p ? q2 : q1) + b * LQ;
    const int* dind = (p ? d2 : d1) + b * RD;

    // ---- token staging: each 256-thread half stages its own pair ----
    {
        const int th = tid & 255;                  // p == tid>>8
        if (th < 32) sQtok[p][th] = (th < LQ) ? qind[th] : -2;
        // padded entries get clamped token; padded quads never reach the bank
        sDtok[p][th] = dind[th < RD ? th : RD - 1];
    }

    // ---- cooperative Q staging: 64 rows (2 pairs x 32), 8 threads/row ----
    {
        const int row = tid >> 3, seg = tid & 7;
        const int qp = row >> 5, prow = row & 31;
        const int* qip = (qp ? q2 : q1) + b * LQ;
        const int qi = qip[prow < LQ ? prow : LQ - 1];
        const float4* pt = reinterpret_cast<const float4*>(emb + (size_t)qi * DIM + seg * 16);
        float4 v0 = pt[0], v1 = pt[1], v2 = pt[2], v3 = pt[3];
        float s0 = 0.f, s1 = 0.f, s2 = 0.f, s3 = 0.f;
        s0 = fmaf(v0.x, v0.x, fmaf(v0.y, v0.y, s0)); s1 = fmaf(v0.z, v0.z, fmaf(v0.w, v0.w, s1));
        s2 = fmaf(v1.x, v1.x, fmaf(v1.y, v1.y, s2)); s3 = fmaf(v1.z, v1.z, fmaf(v1.w, v1.w, s3));
        s0 = fmaf(v2.x, v2.x, fmaf(v2.y, v2.y, s0)); s1 = fmaf(v2.z, v2.z, fmaf(v2.w, v2.w, s1));
        s2 = fmaf(v3.x, v3.x, fmaf(v3.y, v3.y, s2)); s3 = fmaf(v3.z, v3.z, fmaf(v3.w, v3.w, s3));
        float ss = (s0 + s1) + (s2 + s3);
        ss += __shfl_xor(ss, 1);                   // 8-thread row group (tid bits 0..2)
        ss += __shfl_xor(ss, 2);
        ss += __shfl_xor(ss, 4);
        const float inv = rsqrtf(fmaxf(ss, 1e-24f));
        int4 t0, t1;
        t0.x = (int)pk2h(v0.x * inv, v0.y * inv);
        t0.y = (int)pk2h(v0.z * inv, v0.w * inv);
        t0.z = (int)pk2h(v1.x * inv, v1.y * inv);
        t0.w = (int)pk2h(v1.z * inv, v1.w * inv);
        t1.x = (int)pk2h(v2.x * inv, v2.y * inv);
        t1.y = (int)pk2h(v2.z * inv, v2.w * inv);
        t1.z = (int)pk2h(v3.x * inv, v3.y * inv);
        t1.w = (int)pk2h(v3.z * inv, v3.w * inv);
        const int rw = prow & 15;                  // XOR-swizzle (rule 21: both sides)
        sQ[qp][prow][(2 * seg) ^ rw]     = t0;
        sQ[qp][prow][(2 * seg + 1) ^ rw] = t1;
    }
    __syncthreads();                               // tokens + sQ ready

    // ---- Q frags from LDS (swizzled read, conflict-free), held in regs ----
    int4 qa[4], qb[4];
#pragma unroll
    for (int ks = 0; ks < 4; ++ks) {
        qa[ks] = sQ[p][r][(ks * 4 + g) ^ r];
        qb[ks] = sQ[p][16 + r][(ks * 4 + g) ^ r];
    }
    const int qt0 = sQtok[p][r], qt1 = sQtok[p][16 + r];
    const int4* sDtok4 = (const int4*)sDtok[p];

    f32x2 ks0[10], ks1[10];
#pragma unroll
    for (int k = 0; k < 10; ++k) { ks0[k] = f32x2{0.f, 0.f}; ks1[k] = f32x2{0.f, 0.f}; }
    float cnt0 = 0.0f, cnt1 = 0.0f;

    auto strip = [&](int sbase) {
        const int di = sDtok[p][sbase + r];
        int4 df[4];
        gather_row_f16(emb + (size_t)di * DIM, g, df);
        f32x4 acc0 = {0.f, 0.f, 0.f, 0.f}, acc1 = {0.f, 0.f, 0.f, 0.f};
        __builtin_amdgcn_s_setprio(1);             // T5: favor MFMA cluster
#pragma unroll
        for (int ks = 0; ks < 4; ++ks) {
            f16x8 fd = as_hfrag(df[ks]);
            acc0 = __builtin_amdgcn_mfma_f32_16x16x32_f16(fd, as_hfrag(qa[ks]), acc0, 0, 0, 0);
            acc1 = __builtin_amdgcn_mfma_f32_16x16x32_f16(fd, as_hfrag(qb[ks]), acc1, 0, 0, 0);
        }
        __builtin_amdgcn_s_setprio(0);
        // acc element j <-> dcol = sbase + g*4 + j ; qrow = r (+16 for acc1)
        if (sbase + g * 4 < RD) {                  // RD%4==0 -> quad all-or-none
            const int4 dt = sDtok4[(sbase >> 2) + g];
            bank4_pk(acc0, dt, qt0, ks0, cnt0);
            bank4_pk(acc1, dt, qt1, ks1, cnt1);
        }
    };

    if (wl < 3) {
#pragma unroll 2
        for (int s = 0; s < 4; ++s) strip(wl * 64 + s * 16);
    } else {
        strip(192);
    }

    // ---- reduce over g (xor16, xor32), writer lanes g==0 ----
#pragma unroll
    for (int k = 0; k < 10; ++k) {
        float a0 = ks0[k].x, b0 = ks0[k].y, a1 = ks1[k].x, b1 = ks1[k].y;
        a0 += __shfl_xor(a0, 16); a0 += __shfl_xor(a0, 32);
        b0 += __shfl_xor(b0, 16); b0 += __shfl_xor(b0, 32);
        a1 += __shfl_xor(a1, 16); a1 += __shfl_xor(a1, 32);
        b1 += __shfl_xor(b1, 16); b1 += __shfl_xor(b1, 32);
        ks0[k] = f32x2{a0, b0};
        ks1[k] = f32x2{a1, b1};
    }
    cnt0 += __shfl_xor(cnt0, 16); cnt0 += __shfl_xor(cnt0, 32);
    cnt1 += __shfl_xor(cnt1, 16); cnt1 += __shfl_xor(cnt1, 32);

    if (lane < 16) {
        float* k0 = &kred[p][wl][r][0];
        float* k1 = &kred[p][wl][16 + r][0];
#pragma unroll
        for (int k = 0; k < 10; ++k) {
            k0[k] = ks0[k].x;  k0[10 + k] = ks0[k].y;
            k1[k] = ks1[k].x;  k1[10 + k] = ks1[k].y;
        }
        k0[20] = cnt0;
        k1[20] = cnt1;
    }
    __syncthreads();

    // ---- combine: waves 0 and 4 each produce their pair's logit ----
    if (wl == 0) {
        float part = 0.0f;
        if (lane < LQ) {
#pragma unroll
            for (int k = 0; k < KN; ++k) {
                float s = kred[p][0][lane][k] + kred[p][1][lane][k]
                        + kred[p][2][lane][k] + kred[p][3][lane][k];
                float sc = 1.0f;
                if (k < 20) {
                    float j = (float)((k < 10) ? k : k - 10) - 4.5f;
                    sc = EXP2F(-0.721347520f * j * j);   // B_j (compile-time)
                }
                part += W[k] * log1pf(sc * s);
            }
        }
        part += __shfl_xor(part, 1);
        part += __shfl_xor(part, 2);
        part += __shfl_xor(part, 4);
        part += __shfl_xor(part, 8);
        part += __shfl_xor(part, 16);
        part += __shfl_xor(part, 32);
        if (lane == 0) lgbuf[p] = part;            // bias cancels in the difference
    }
    __syncthreads();

    if (tid == 0) {
        float x = lgbuf[0] - lgbuf[1];
        out[b] = 1.0f / (1.0f + expf(-x));
    }
}

extern "C" void kernel_launch(void* const* d_in, const int* in_sizes, int n_in,
                              void* d_out, int out_size, void* d_ws, size_t ws_size,
                              hipStream_t stream) {
    const float* emb = (const float*)d_in[0];
    const float* W   = (const float*)d_in[1];
    const int* q1    = (const int*)d_in[3];
    const int* dd1   = (const int*)d_in[4];
    const int* q2    = (const int*)d_in[5];
    const int* dd2   = (const int*)d_in[6];

    knrm_main<<<BB, 512, 0, stream>>>(emb, W, q1, dd1, q2, dd2, (float*)d_out);
}

// Round 20
// 33.726 us; speedup vs baseline: 1.0260x; 1.0260x over previous
//
#include <hip/hip_runtime.h>
#include <hip/hip_fp16.h>
#include <math.h>

#define V   50000
#define DIM 128
#define BB  512
#define LQ  30
#define RD  200
#define KN  21

typedef __attribute__((ext_vector_type(8))) _Float16 f16x8;  // 8 f16 = 4 VGPRs
typedef __attribute__((ext_vector_type(4))) float f32x4;
typedef __attribute__((ext_vector_type(2))) float f32x2;     // -> v_pk_*_f32

#if __has_builtin(__builtin_amdgcn_exp2f)
#define EXP2F(x) __builtin_amdgcn_exp2f(x)
#else
#define EXP2F(x) __expf((x) * 0.69314718f)
#endif

#define ALPHA 72.1347520f       // 50 * log2(e)
#define E10   22026.4657948f    // 2^(0.2*ALPHA) = e^10

static __device__ __forceinline__ f16x8 as_hfrag(int4 v) {
    return __builtin_bit_cast(f16x8, v);
}
static __device__ __forceinline__ unsigned pk2h(float a, float b) {
    return __builtin_bit_cast(unsigned, __builtin_amdgcn_cvt_pkrtz(a, b));
}
static __device__ __forceinline__ unsigned hscale(unsigned u, __half2 s) {
    return __builtin_bit_cast(unsigned, __hmul2(__builtin_bit_cast(__half2, u), s));
}

// Fused gather+normalize+f16-convert of one embedding row (doc side).
// Lanes (r, g=0..3) jointly hold the row; lane slice = elements ks*32+g*8..+7.
// ss reduced across g via shfl_xor 16/32. RTZ-pack first, then f16 scale.
static __device__ __forceinline__ void gather_row_f16(const float* __restrict__ rowp,
                                                      int g, int4* f) {
    float ss = 0.0f;
#pragma unroll
    for (int ks = 0; ks < 4; ++ks) {
        const float4* p = reinterpret_cast<const float4*>(rowp + ks * 32 + g * 8);
        float4 a = p[0], b = p[1];
        ss = fmaf(a.x, a.x, fmaf(a.y, a.y, fmaf(a.z, a.z, fmaf(a.w, a.w, ss))));
        ss = fmaf(b.x, b.x, fmaf(b.y, b.y, fmaf(b.z, b.z, fmaf(b.w, b.w, ss))));
        f[ks].x = (int)pk2h(a.x, a.y);
        f[ks].y = (int)pk2h(a.z, a.w);
        f[ks].z = (int)pk2h(b.x, b.y);
        f[ks].w = (int)pk2h(b.z, b.w);
    }
    ss += __shfl_xor(ss, 16);
    ss += __shfl_xor(ss, 32);
    const float inv = rsqrtf(fmaxf(ss, 1e-24f));
    const __half2 h2 = __float2half2_rn(inv);
#pragma unroll
    for (int ks = 0; ks < 4; ++ks) {
        f[ks].x = (int)hscale((unsigned)f[ks].x, h2);
        f[ks].y = (int)hscale((unsigned)f[ks].y, h2);
        f[ks].z = (int)hscale((unsigned)f[ks].z, h2);
        f[ks].w = (int)hscale((unsigned)f[ks].w, h2);
    }
}

// Two-leg geometric Gaussian bank (verified R6..R18), packed f32x2
// (x = leg A, kernels 0..9 center mu=-0.5; y = leg B, 10..19 center +0.5),
// 4 independent t*u chains, tree summation. B_j folded in at combine.
// Exact kernel (mu=1, sigma=1e-3) = integer token equality count.
static __device__ __forceinline__ void bank4_pk(f32x4 pv, int4 dt, int qt,
                                                f32x2* ks2, float& cnt) {
    const float mv[4] = {pv[0], pv[1], pv[2], pv[3]};
    const int   dv[4] = {dt.x, dt.y, dt.z, dt.w};
    f32x2 t[4], u[4];
#pragma unroll
    for (int i = 0; i < 4; ++i) {
        float m  = mv[i];
        float dA = m + 0.5f, dB = m - 0.5f;
        float tA = EXP2F(-ALPHA * dA * (dA + 0.9f));   // leg A start (k=0)
        float tB = EXP2F(-ALPHA * dB * (dB + 0.9f));   // leg B start (k=10)
        float uB = EXP2F(14.4269504f * dB);            // 2^(0.2*ALPHA*dB)
        float uA = uB * E10;
        t[i] = f32x2{tA, tB};
        u[i] = f32x2{uA, uB};
        cnt += (dv[i] == qt) ? 1.0f : 0.0f;
    }
#pragma unroll
    for (int k = 0; k < 10; ++k) {
        ks2[k] += (t[0] + t[1]) + (t[2] + t[3]);       // tree: short dep chains
        t[0] *= u[0]; t[1] *= u[1]; t[2] *= u[2]; t[3] *= u[3];
    }
}

// ------------- kernel: fused-norm swapped-operand KNRM, cooperative Q staging -------
// 1024 blocks (pair*b) x 256 thr (4 waves). Wave w owns doc cols w*64..+63
// (4 strips of 16; wave 3: 1 strip). mfma(A=D_frag, B=Q_frag): C row = dcol
// (g*4+j), C col = qrow (r) -> bank consumes accumulators from registers.
// Q rows normalized ONCE per block into an XOR-swizzled 8KB LDS f16 tile.
// Doc rows fused-gathered per strip. In-block combine -> logit.
__global__ __launch_bounds__(256, 4) void knrm_main(
    const float* __restrict__ emb, const float* __restrict__ W,
    const int* __restrict__ q1, const int* __restrict__ d1,
    const int* __restrict__ q2, const int* __restrict__ d2,
    float* __restrict__ logits)
{
    __shared__ int sQtok[32];
    __shared__ __align__(16) int sDtok[256];
    __shared__ int4 sQ[32][16];                    // 32 rows x 256B f16, swizzled
    __shared__ float kred[4][32][KN];              // 10752 B

    const int pb = blockIdx.x;
    const int pair = pb >> 9, b = pb & 511;
    const int* qind = (pair ? q2 : q1) + b * LQ;
    const int* dind = (pair ? d2 : d1) + b * RD;

    const int tid = threadIdx.x;
    const int lane = tid & 63, w = tid >> 6;
    const int r = lane & 15, g = lane >> 4;

    if (tid < 32) sQtok[tid] = (tid < LQ) ? qind[tid] : -2;
    // padded entries get clamped token; padded quads never reach the bank
    sDtok[tid] = dind[tid < RD ? tid : RD - 1];

    // ---- cooperative Q staging: row = tid>>3, 16 elems per thread ----
    {
        const int row = tid >> 3, seg = tid & 7;
        const int qi = qind[row < LQ ? row : LQ - 1];
        const float4* p = reinterpret_cast<const float4*>(emb + (size_t)qi * DIM + seg * 16);
        float4 v0 = p[0], v1 = p[1], v2 = p[2], v3 = p[3];
        float s0 = 0.f, s1 = 0.f, s2 = 0.f, s3 = 0.f;
        s0 = fmaf(v0.x, v0.x, fmaf(v0.y, v0.y, s0)); s1 = fmaf(v0.z, v0.z, fmaf(v0.w, v0.w, s1));
        s2 = fmaf(v1.x, v1.x, fmaf(v1.y, v1.y, s2)); s3 = fmaf(v1.z, v1.z, fmaf(v1.w, v1.w, s3));
        s0 = fmaf(v2.x, v2.x, fmaf(v2.y, v2.y, s0)); s1 = fmaf(v2.z, v2.z, fmaf(v2.w, v2.w, s1));
        s2 = fmaf(v3.x, v3.x, fmaf(v3.y, v3.y, s2)); s3 = fmaf(v3.z, v3.z, fmaf(v3.w, v3.w, s3));
        float ss = (s0 + s1) + (s2 + s3);
        ss += __shfl_xor(ss, 1);
        ss += __shfl_xor(ss, 2);
        ss += __shfl_xor(ss, 4);
        const float inv = rsqrtf(fmaxf(ss, 1e-24f));
        int4 t0, t1;
        t0.x = (int)pk2h(v0.x * inv, v0.y * inv);
        t0.y = (int)pk2h(v0.z * inv, v0.w * inv);
        t0.z = (int)pk2h(v1.x * inv, v1.y * inv);
        t0.w = (int)pk2h(v1.z * inv, v1.w * inv);
        t1.x = (int)pk2h(v2.x * inv, v2.y * inv);
        t1.y = (int)pk2h(v2.z * inv, v2.w * inv);
        t1.z = (int)pk2h(v3.x * inv, v3.y * inv);
        t1.w = (int)pk2h(v3.z * inv, v3.w * inv);
        const int rw = row & 15;                   // XOR-swizzle (rule 21: both sides)
        sQ[row][(2 * seg) ^ rw]     = t0;
        sQ[row][(2 * seg + 1) ^ rw] = t1;
    }
    __syncthreads();                               // tokens + sQ ready (only barrier)

    // ---- Q frags from LDS (swizzled read, conflict-free) ----
    int4 qa[4], qb[4];
#pragma unroll
    for (int ks = 0; ks < 4; ++ks) {
        qa[ks] = sQ[r][(ks * 4 + g) ^ r];
        qb[ks] = sQ[16 + r][(ks * 4 + g) ^ r];
    }
    const int qt0 = sQtok[r], qt1 = sQtok[16 + r];
    const int4* sDtok4 = (const int4*)sDtok;

    f32x2 ks0[10], ks1[10];
#pragma unroll
    for (int k = 0; k < 10; ++k) { ks0[k] = f32x2{0.f, 0.f}; ks1[k] = f32x2{0.f, 0.f}; }
    float cnt0 = 0.0f, cnt1 = 0.0f;

    auto strip = [&](int sbase) {
        const int di = sDtok[sbase + r];
        int4 df[4];
        gather_row_f16(emb + (size_t)di * DIM, g, df);
        f32x4 acc0 = {0.f, 0.f, 0.f, 0.f}, acc1 = {0.f, 0.f, 0.f, 0.f};
#pragma unroll
        for (int ks = 0; ks < 4; ++ks) {
            f16x8 fd = as_hfrag(df[ks]);
            acc0 = __builtin_amdgcn_mfma_f32_16x16x32_f16(fd, as_hfrag(qa[ks]), acc0, 0, 0, 0);
            acc1 = __builtin_amdgcn_mfma_f32_16x16x32_f16(fd, as_hfrag(qb[ks]), acc1, 0, 0, 0);
        }
        // acc element j <-> dcol = sbase + g*4 + j ; qrow = r (+16 for acc1)
        if (sbase + g * 4 < RD) {                  // RD%4==0 -> quad all-or-none
            const int4 dt = sDtok4[(sbase >> 2) + g];
            bank4_pk(acc0, dt, qt0, ks0, cnt0);
            bank4_pk(acc1, dt, qt1, ks1, cnt1);
        }
    };

    if (w < 3) {
#pragma unroll 2
        for (int s = 0; s < 4; ++s) strip(w * 64 + s * 16);
    } else {
        strip(192);
    }

    // ---- reduce over g (xor16, xor32), writer lanes g==0 ----
#pragma unroll
    for (int k = 0; k < 10; ++k) {
        float a0 = ks0[k].x, b0 = ks0[k].y, a1 = ks1[k].x, b1 = ks1[k].y;
        a0 += __shfl_xor(a0, 16); a0 += __shfl_xor(a0, 32);
        b0 += __shfl_xor(b0, 16); b0 += __shfl_xor(b0, 32);
        a1 += __shfl_xor(a1, 16); a1 += __shfl_xor(a1, 32);
        b1 += __shfl_xor(b1, 16); b1 += __shfl_xor(b1, 32);
        ks0[k] = f32x2{a0, b0};
        ks1[k] = f32x2{a1, b1};
    }
    cnt0 += __shfl_xor(cnt0, 16); cnt0 += __shfl_xor(cnt0, 32);
    cnt1 += __shfl_xor(cnt1, 16); cnt1 += __shfl_xor(cnt1, 32);

    if (lane < 16) {
        float* k0 = &kred[w][r][0];
        float* k1 = &kred[w][16 + r][0];
#pragma unroll
        for (int k = 0; k < 10; ++k) {
            k0[k] = ks0[k].x;  k0[10 + k] = ks0[k].y;
            k1[k] = ks1[k].x;  k1[10 + k] = ks1[k].y;
        }
        k0[20] = cnt0;
        k1[20] = cnt1;
    }
    __syncthreads();

    // ---- in-block combine: B_j scale, log1p, W-dot, row reduce -> logit ----
    if (tid < 64) {
        float part = 0.0f;
        if (tid < LQ) {
#pragma unroll
            for (int k = 0; k < KN; ++k) {
                float s = kred[0][tid][k] + kred[1][tid][k]
                        + kred[2][tid][k] + kred[3][tid][k];
                float sc = 1.0f;
                if (k < 20) {
                    float j = (float)((k < 10) ? k : k - 10) - 4.5f;
                    sc = EXP2F(-0.721347520f * j * j);   // B_j (compile-time)
                }
                part += W[k] * log1pf(sc * s);
            }
        }
        part += __shfl_xor(part, 1);
        part += __shfl_xor(part, 2);
        part += __shfl_xor(part, 4);
        part += __shfl_xor(part, 8);
        part += __shfl_xor(part, 16);
        part += __shfl_xor(part, 32);
        if (tid == 0) logits[pair * BB + b] = part;   // bias cancels in diff
    }
}

// ------------- kernel 2: sigmoid of logit difference -------------
__global__ void knrm_final(const float* __restrict__ logits, float* __restrict__ out) {
    int i = blockIdx.x * blockDim.x + threadIdx.x;
    if (i < BB) {
        float x = logits[i] - logits[BB + i];
        out[i] = 1.0f / (1.0f + expf(-x));
    }
}

extern "C" void kernel_launch(void* const* d_in, const int* in_sizes, int n_in,
                              void* d_out, int out_size, void* d_ws, size_t ws_size,
                              hipStream_t stream) {
    const float* emb = (const float*)d_in[0];
    const float* W   = (const float*)d_in[1];
    const int* q1    = (const int*)d_in[3];
    const int* dd1   = (const int*)d_in[4];
    const int* q2    = (const int*)d_in[5];
    const int* dd2   = (const int*)d_in[6];

    float* logits = (float*)d_ws;                    // 1024 floats

    knrm_main<<<1024, 256, 0, stream>>>(emb, W, q1, dd1, q2, dd2, logits);
    knrm_final<<<2, 256, 0, stream>>>(logits, (float*)d_out);
}

// Round 21
// 33.583 us; speedup vs baseline: 1.0304x; 1.0043x over previous
//
#include <hip/hip_runtime.h>
#include <hip/hip_fp16.h>
#include <math.h>

#define V   50000
#define DIM 128
#define BB  512
#define LQ  30
#define RD  200
#define KN  21

typedef __attribute__((ext_vector_type(8))) _Float16 f16x8;  // 8 f16 = 4 VGPRs
typedef __attribute__((ext_vector_type(4))) float f32x4;
typedef __attribute__((ext_vector_type(2))) float f32x2;     // -> v_pk_*_f32

#if __has_builtin(__builtin_amdgcn_exp2f)
#define EXP2F(x) __builtin_amdgcn_exp2f(x)
#else
#define EXP2F(x) __expf((x) * 0.69314718f)
#endif

#define ALPHA 72.1347520f       // 50 * log2(e)
#define E10   22026.4657948f    // 2^(0.2*ALPHA) = e^10

static __device__ __forceinline__ f16x8 as_hfrag(int4 v) {
    return __builtin_bit_cast(f16x8, v);
}
static __device__ __forceinline__ unsigned pk2h(float a, float b) {
    return __builtin_bit_cast(unsigned, __builtin_amdgcn_cvt_pkrtz(a, b));
}
static __device__ __forceinline__ unsigned hscale(unsigned u, __half2 s) {
    return __builtin_bit_cast(unsigned, __hmul2(__builtin_bit_cast(__half2, u), s));
}

// Fused gather+normalize+f16-convert of one embedding row (doc side).
// Lanes (r, g=0..3) jointly hold the row; lane slice = elements ks*32+g*8..+7.
// ss reduced across g via shfl_xor 16/32. RTZ-pack first, then f16 scale.
static __device__ __forceinline__ void gather_row_f16(const float* __restrict__ rowp,
                                                      int g, int4* f) {
    float ss = 0.0f;
#pragma unroll
    for (int ks = 0; ks < 4; ++ks) {
        const float4* p = reinterpret_cast<const float4*>(rowp + ks * 32 + g * 8);
        float4 a = p[0], b = p[1];
        ss = fmaf(a.x, a.x, fmaf(a.y, a.y, fmaf(a.z, a.z, fmaf(a.w, a.w, ss))));
        ss = fmaf(b.x, b.x, fmaf(b.y, b.y, fmaf(b.z, b.z, fmaf(b.w, b.w, ss))));
        f[ks].x = (int)pk2h(a.x, a.y);
        f[ks].y = (int)pk2h(a.z, a.w);
        f[ks].z = (int)pk2h(b.x, b.y);
        f[ks].w = (int)pk2h(b.z, b.w);
    }
    ss += __shfl_xor(ss, 16);
    ss += __shfl_xor(ss, 32);
    const float inv = rsqrtf(fmaxf(ss, 1e-24f));
    const __half2 h2 = __float2half2_rn(inv);
#pragma unroll
    for (int ks = 0; ks < 4; ++ks) {
        f[ks].x = (int)hscale((unsigned)f[ks].x, h2);
        f[ks].y = (int)hscale((unsigned)f[ks].y, h2);
        f[ks].z = (int)hscale((unsigned)f[ks].z, h2);
        f[ks].w = (int)hscale((unsigned)f[ks].w, h2);
    }
}

// Two-leg geometric Gaussian bank (verified R6..R20), packed f32x2
// (x = leg A, kernels 0..9 center mu=-0.5; y = leg B, 10..19 center +0.5),
// 4 independent t*u chains, tree summation. B_j folded in at combine.
// Exact kernel (mu=1, sigma=1e-3) = integer token equality count.
static __device__ __forceinline__ void bank4_pk(f32x4 pv, int4 dt, int qt,
                                                f32x2* ks2, float& cnt) {
    const float mv[4] = {pv[0], pv[1], pv[2], pv[3]};
    const int   dv[4] = {dt.x, dt.y, dt.z, dt.w};
    f32x2 t[4], u[4];
#pragma unroll
    for (int i = 0; i < 4; ++i) {
        float m  = mv[i];
        float dA = m + 0.5f, dB = m - 0.5f;
        float tA = EXP2F(-ALPHA * dA * (dA + 0.9f));   // leg A start (k=0)
        float tB = EXP2F(-ALPHA * dB * (dB + 0.9f));   // leg B start (k=10)
        float uB = EXP2F(14.4269504f * dB);            // 2^(0.2*ALPHA*dB)
        float uA = uB * E10;
        t[i] = f32x2{tA, tB};
        u[i] = f32x2{uA, uB};
        cnt += (dv[i] == qt) ? 1.0f : 0.0f;
    }
#pragma unroll
    for (int k = 0; k < 10; ++k) {
        ks2[k] += (t[0] + t[1]) + (t[2] + t[3]);       // tree: short dep chains
        t[0] *= u[0]; t[1] *= u[1]; t[2] *= u[2]; t[3] *= u[3];
    }
}

// ------------- kernel: fused-norm swapped-operand KNRM, balanced strips -------------
// 1024 blocks (pair*b) x 256 thr (4 waves). Strip schedule 3.5/3/3/3 (was
// 4/4/4/1): wave 0 -> {0,16,32} + half-strip 192; wave w>0 -> {48w, +16, +32}.
// Critical path 4 -> 3.5 strips. mfma(A=D_frag, B=Q_frag): C row = dcol
// (g*4+j), C col = qrow (r) -> bank consumes accumulators from registers.
// Q rows normalized ONCE per block into an XOR-swizzled 8KB LDS f16 tile.
__global__ __launch_bounds__(256, 4) void knrm_main(
    const float* __restrict__ emb, const float* __restrict__ W,
    const int* __restrict__ q1, const int* __restrict__ d1,
    const int* __restrict__ q2, const int* __restrict__ d2,
    float* __restrict__ logits)
{
    __shared__ int sQtok[32];
    __shared__ __align__(16) int sDtok[256];
    __shared__ int4 sQ[32][16];                    // 32 rows x 256B f16, swizzled
    __shared__ float kred[4][32][KN];              // 10752 B

    const int pb = blockIdx.x;
    const int pair = pb >> 9, b = pb & 511;
    const int* qind = (pair ? q2 : q1) + b * LQ;
    const int* dind = (pair ? d2 : d1) + b * RD;

    const int tid = threadIdx.x;
    const int lane = tid & 63, w = tid >> 6;
    const int r = lane & 15, g = lane >> 4;

    if (tid < 32) sQtok[tid] = (tid < LQ) ? qind[tid] : -2;
    // padded entries get clamped token; padded quads never reach the bank
    sDtok[tid] = dind[tid < RD ? tid : RD - 1];

    // ---- cooperative Q staging: row = tid>>3, 16 elems per thread ----
    {
        const int row = tid >> 3, seg = tid & 7;
        const int qi = qind[row < LQ ? row : LQ - 1];
        const float4* p = reinterpret_cast<const float4*>(emb + (size_t)qi * DIM + seg * 16);
        float4 v0 = p[0], v1 = p[1], v2 = p[2], v3 = p[3];
        float s0 = 0.f, s1 = 0.f, s2 = 0.f, s3 = 0.f;
        s0 = fmaf(v0.x, v0.x, fmaf(v0.y, v0.y, s0)); s1 = fmaf(v0.z, v0.z, fmaf(v0.w, v0.w, s1));
        s2 = fmaf(v1.x, v1.x, fmaf(v1.y, v1.y, s2)); s3 = fmaf(v1.z, v1.z, fmaf(v1.w, v1.w, s3));
        s0 = fmaf(v2.x, v2.x, fmaf(v2.y, v2.y, s0)); s1 = fmaf(v2.z, v2.z, fmaf(v2.w, v2.w, s1));
        s2 = fmaf(v3.x, v3.x, fmaf(v3.y, v3.y, s2)); s3 = fmaf(v3.z, v3.z, fmaf(v3.w, v3.w, s3));
        float ss = (s0 + s1) + (s2 + s3);
        ss += __shfl_xor(ss, 1);
        ss += __shfl_xor(ss, 2);
        ss += __shfl_xor(ss, 4);
        const float inv = rsqrtf(fmaxf(ss, 1e-24f));
        int4 t0, t1;
        t0.x = (int)pk2h(v0.x * inv, v0.y * inv);
        t0.y = (int)pk2h(v0.z * inv, v0.w * inv);
        t0.z = (int)pk2h(v1.x * inv, v1.y * inv);
        t0.w = (int)pk2h(v1.z * inv, v1.w * inv);
        t1.x = (int)pk2h(v2.x * inv, v2.y * inv);
        t1.y = (int)pk2h(v2.z * inv, v2.w * inv);
        t1.z = (int)pk2h(v3.x * inv, v3.y * inv);
        t1.w = (int)pk2h(v3.z * inv, v3.w * inv);
        const int rw = row & 15;                   // XOR-swizzle (rule 21: both sides)
        sQ[row][(2 * seg) ^ rw]     = t0;
        sQ[row][(2 * seg + 1) ^ rw] = t1;
    }
    __syncthreads();                               // tokens + sQ ready (only barrier)

    // ---- Q frags from LDS (swizzled read, conflict-free) ----
    int4 qa[4], qb[4];
#pragma unroll
    for (int ks = 0; ks < 4; ++ks) {
        qa[ks] = sQ[r][(ks * 4 + g) ^ r];
        qb[ks] = sQ[16 + r][(ks * 4 + g) ^ r];
    }
    const int qt0 = sQtok[r], qt1 = sQtok[16 + r];
    const int4* sDtok4 = (const int4*)sDtok;

    f32x2 ks0[10], ks1[10];
#pragma unroll
    for (int k = 0; k < 10; ++k) { ks0[k] = f32x2{0.f, 0.f}; ks1[k] = f32x2{0.f, 0.f}; }
    float cnt0 = 0.0f, cnt1 = 0.0f;

    auto strip = [&](int sbase) {
        const int di = sDtok[sbase + r];
        int4 df[4];
        gather_row_f16(emb + (size_t)di * DIM, g, df);
        f32x4 acc0 = {0.f, 0.f, 0.f, 0.f}, acc1 = {0.f, 0.f, 0.f, 0.f};
#pragma unroll
        for (int ks = 0; ks < 4; ++ks) {
            f16x8 fd = as_hfrag(df[ks]);
            acc0 = __builtin_amdgcn_mfma_f32_16x16x32_f16(fd, as_hfrag(qa[ks]), acc0, 0, 0, 0);
            acc1 = __builtin_amdgcn_mfma_f32_16x16x32_f16(fd, as_hfrag(qb[ks]), acc1, 0, 0, 0);
        }
        // acc element j <-> dcol = sbase + g*4 + j ; qrow = r (+16 for acc1)
        if (sbase + g * 4 < RD) {                  // RD%4==0 -> quad all-or-none
            const int4 dt = sDtok4[(sbase >> 2) + g];
            bank4_pk(acc0, dt, qt0, ks0, cnt0);
            bank4_pk(acc1, dt, qt1, ks1, cnt1);
        }
    };

    // ---- balanced schedule: w0 -> 0,16,32 + half-strip 192; w>0 -> 48w.. ----
    if (w == 0) {
        strip(0);
        strip(16);
        strip(32);
        strip(192);                                // cols 192..199 (quads g<2 live)
    } else {
        const int base = 48 * w;                   // 48 / 96 / 144
        strip(base);
        strip(base + 16);
        strip(base + 32);
    }

    // ---- reduce over g (xor16, xor32), writer lanes g==0 ----
#pragma unroll
    for (int k = 0; k < 10; ++k) {
        float a0 = ks0[k].x, b0 = ks0[k].y, a1 = ks1[k].x, b1 = ks1[k].y;
        a0 += __shfl_xor(a0, 16); a0 += __shfl_xor(a0, 32);
        b0 += __shfl_xor(b0, 16); b0 += __shfl_xor(b0, 32);
        a1 += __shfl_xor(a1, 16); a1 += __shfl_xor(a1, 32);
        b1 += __shfl_xor(b1, 16); b1 += __shfl_xor(b1, 32);
        ks0[k] = f32x2{a0, b0};
        ks1[k] = f32x2{a1, b1};
    }
    cnt0 += __shfl_xor(cnt0, 16); cnt0 += __shfl_xor(cnt0, 32);
    cnt1 += __shfl_xor(cnt1, 16); cnt1 += __shfl_xor(cnt1, 32);

    if (lane < 16) {
        float* k0 = &kred[w][r][0];
        float* k1 = &kred[w][16 + r][0];
#pragma unroll
        for (int k = 0; k < 10; ++k) {
            k0[k] = ks0[k].x;  k0[10 + k] = ks0[k].y;
            k1[k] = ks1[k].x;  k1[10 + k] = ks1[k].y;
        }
        k0[20] = cnt0;
        k1[20] = cnt1;
    }
    __syncthreads();

    // ---- in-block combine: B_j scale, log1p, W-dot, row reduce -> logit ----
    if (tid < 64) {
        float part = 0.0f;
        if (tid < LQ) {
#pragma unroll
            for (int k = 0; k < KN; ++k) {
                float s = kred[0][tid][k] + kred[1][tid][k]
                        + kred[2][tid][k] + kred[3][tid][k];
                float sc = 1.0f;
                if (k < 20) {
                    float j = (float)((k < 10) ? k : k - 10) - 4.5f;
                    sc = EXP2F(-0.721347520f * j * j);   // B_j (compile-time)
                }
                part += W[k] * log1pf(sc * s);
            }
        }
        part += __shfl_xor(part, 1);
        part += __shfl_xor(part, 2);
        part += __shfl_xor(part, 4);
        part += __shfl_xor(part, 8);
        part += __shfl_xor(part, 16);
        part += __shfl_xor(part, 32);
        if (tid == 0) logits[pair * BB + b] = part;   // bias cancels in diff
    }
}

// ------------- kernel 2: sigmoid of logit difference -------------
__global__ void knrm_final(const float* __restrict__ logits, float* __restrict__ out) {
    int i = blockIdx.x * blockDim.x + threadIdx.x;
    if (i < BB) {
        float x = logits[i] - logits[BB + i];
        out[i] = 1.0f / (1.0f + expf(-x));
    }
}

extern "C" void kernel_launch(void* const* d_in, const int* in_sizes, int n_in,
                              void* d_out, int out_size, void* d_ws, size_t ws_size,
                              hipStream_t stream) {
    const float* emb = (const float*)d_in[0];
    const float* W   = (const float*)d_in[1];
    const int* q1    = (const int*)d_in[3];
    const int* dd1   = (const int*)d_in[4];
    const int* q2    = (const int*)d_in[5];
    const int* dd2   = (const int*)d_in[6];

    float* logits = (float*)d_ws;                    // 1024 floats

    knrm_main<<<1024, 256, 0, stream>>>(emb, W, q1, dd1, q2, dd2, logits);
    knrm_final<<<2, 256, 0, stream>>>(logits, (float*)d_out);
}